// Round 6
// baseline (6411.122 us; speedup 1.0000x reference)
//
#include <hip/hip_runtime.h>
#include <hip/hip_cooperative_groups.h>
#include <math.h>

namespace cg = cooperative_groups;

typedef short bf16x8 __attribute__((ext_vector_type(8)));
typedef float f32x4 __attribute__((ext_vector_type(4)));

#define B 8
#define NS 4096
#define NC 256
#define TH 8
#define TP 24
#define T_ALL 32
#define DIN 28
#define DM 27
#define G 64
#define H 64
#define NG3 192
#define NSTEP 31

#define NBLK 512
#define NTHR 512
#define SROWS 64          // station rows per block
#define CROWS 4           // city rows per block
#define ROWS 68
#define BUFW 65
#define XCW 160           // xcat K width (92 x|xg + 64 h + 1 bias + 3 pad)
#define KIT 5             // K-iters of 32
#define NT 16             // N tiles (256 gate cols)
#define WFRAG (KIT*NT*64*8)   // 40960 bf16 per weight array

#define WS_ELL 64
#define WF_ELL 32
#define WFT_ELL 128

struct Params {
  const float *x_hist, *feat_s, *c_x_hist, *feat_c, *adj_s, *adj_c, *afc;
  const float *conv_w, *conv_b, *c_conv_w, *c_conv_b;
  const float *gru_wi, *gru_wh, *gru_bi, *gru_bh;
  const float *c_gru_wi, *c_gru_wh, *c_gru_bi, *c_gru_bh;
  const float *fc_w, *fc_b, *c_fc_w, *c_fc_b;
  const float *c2s_w, *c2s_b, *s2c_w, *s2c_b;
  int *deg_s, *ellc_s; float *ellv_s, *dinv_s;
  int *deg_c, *ellc_c; float *ellv_c, *dinv_c;
  int *degf, *ellf;
  int *degfT, *ellfT;
  float *xg_s, *xg_c, *xp_s, *xp_c;
  float *xcat;                       // [NBLK][ROWS][XCW] fp32
  unsigned short *wSh, *wSl, *wCh, *wCl;  // fragment-ordered Wcat bf16 hi/lo
  float *out;
};

struct Smem {
  union {
    struct { float xa[ROWS][DIN]; float lx[ROWS][DIN]; } a;
    float buf[ROWS][BUFW];
  } u;
  float cityfc[4][4];
  float fcS[SROWS][2];
};

__device__ __forceinline__ float sigm_(float x) { return 1.0f / (1.0f + expf(-x)); }

__device__ __forceinline__ unsigned short bf16rn(float f) {
  unsigned u = __float_as_uint(f);
  u += 0x7fffu + ((u >> 16) & 1u);
  return (unsigned short)(u >> 16);
}
__device__ __forceinline__ float bf16tof(unsigned short h) {
  return __uint_as_float(((unsigned)h) << 16);
}
__device__ __forceinline__ void split8(const float* a, bf16x8& hi, bf16x8& lo) {
#pragma unroll
  for (int j = 0; j < 8; j++) {
    unsigned short h = bf16rn(a[j]);
    hi[j] = (short)h;
    lo[j] = (short)bf16rn(a[j] - bf16tof(h));
  }
}

// Wcat[k][c]: rows 0..91 = wi, 92..155 = wh, 156 = bias, 157..159 = 0.
// cols 0..127 = r,z (x+h fused); 128..191 = xn (wi only); 192..255 = hc (wh only).
__device__ float wcat_val(int k, int c, const float* wi, const float* wh,
                          const float* bi, const float* bh) {
  if (k < 92)  { return (c < 192) ? wi[k * NG3 + c] : 0.0f; }
  if (k < 156) {
    int kk = k - 92;
    if (c < 128) return wh[kk * NG3 + c];
    if (c < 192) return 0.0f;
    return wh[kk * NG3 + (c - 64)];
  }
  if (k == 156) {
    if (c < 128) return bi[c] + bh[c];
    if (c < 192) return bi[c];
    return bh[c - 64];
  }
  return 0.0f;
}

// x channel f of node n at global step.
__device__ __forceinline__ float xval(const Params& p, int sta, int hist, int step,
                                      int b, int n, int f) {
  if (f == 0) {
    if (hist) return sta ? p.x_hist[((size_t)b * TH + step) * NS + n]
                         : p.c_x_hist[((size_t)b * TH + step) * NC + n];
    return sta ? p.xp_s[b * NS + n] : p.xp_c[b * NC + n];
  }
  int tf = step + 1;
  return sta ? p.feat_s[(((size_t)b * T_ALL + tf) * NS + n) * DM + (f - 1)]
             : p.feat_c[(((size_t)b * T_ALL + tf) * NC + n) * DM + (f - 1)];
}

// ---------------- P0: ELL tables + weight fragment prep + xcat init ----------------
__device__ void build_tables(const Params& p, int bid, int tid, int nblk) {
  const int lane = tid & 63;
  const int gw = bid * (NTHR / 64) + (tid >> 6);
  const int nw = nblk * (NTHR / 64);

  for (int r = gw; r < NS; r += nw) {
    int base = 0;
    for (int n0 = 0; n0 < NS; n0 += 64) {
      int n = n0 + lane;
      float v = p.adj_s[(size_t)r * NS + n];
      bool fl = (v != 0.0f) && (n != r);
      unsigned long long m = __ballot(fl);
      if (fl) {
        int pos = base + (int)__popcll(m & ((1ull << lane) - 1ull));
        if (pos < WS_ELL) p.ellc_s[r * WS_ELL + pos] = n;
      }
      base += (int)__popcll(m);
    }
    int deg = base < WS_ELL ? base : WS_ELL;
    for (int s = deg + lane; s < WS_ELL; s += 64) p.ellc_s[r * WS_ELL + s] = 0;
    if (lane == 0) {
      p.deg_s[r] = deg;
      p.dinv_s[r] = base > 0 ? 1.0f / sqrtf((float)base) : 0.0f;
    }
  }
  for (int r = gw; r < NS; r += nw) {
    int base = 0;
    for (int n0 = 0; n0 < NC; n0 += 64) {
      int n = n0 + lane;
      bool fl = p.afc[(size_t)r * NC + n] != 0.0f;
      unsigned long long m = __ballot(fl);
      if (fl) {
        int pos = base + (int)__popcll(m & ((1ull << lane) - 1ull));
        if (pos < WF_ELL) p.ellf[r * WF_ELL + pos] = n;
      }
      base += (int)__popcll(m);
    }
    int deg = base < WF_ELL ? base : WF_ELL;
    for (int s = deg + lane; s < WF_ELL; s += 64) p.ellf[r * WF_ELL + s] = 0;
    if (lane == 0) p.degf[r] = deg;
  }
  for (int r = gw; r < NC; r += nw) {
    int base = 0;
    for (int n0 = 0; n0 < NC; n0 += 64) {
      int n = n0 + lane;
      float v = p.adj_c[(size_t)r * NC + n];
      bool fl = (v != 0.0f) && (n != r);
      unsigned long long m = __ballot(fl);
      if (fl) {
        int pos = base + (int)__popcll(m & ((1ull << lane) - 1ull));
        if (pos < WS_ELL) p.ellc_c[r * WS_ELL + pos] = n;
      }
      base += (int)__popcll(m);
    }
    int deg = base < WS_ELL ? base : WS_ELL;
    for (int s = deg + lane; s < WS_ELL; s += 64) p.ellc_c[r * WS_ELL + s] = 0;
    if (lane == 0) {
      p.deg_c[r] = deg;
      p.dinv_c[r] = base > 0 ? 1.0f / sqrtf((float)base) : 0.0f;
    }
  }
  for (int r = gw; r < NC; r += nw) {
    int base = 0;
    for (int n0 = 0; n0 < NS; n0 += 64) {
      int n = n0 + lane;
      bool fl = p.afc[(size_t)n * NC + r] != 0.0f;
      unsigned long long m = __ballot(fl);
      if (fl) {
        int pos = base + (int)__popcll(m & ((1ull << lane) - 1ull));
        if (pos < WFT_ELL) p.ellfT[r * WFT_ELL + pos] = n;
      }
      base += (int)__popcll(m);
    }
    int deg = base < WFT_ELL ? base : WFT_ELL;
    for (int s = deg + lane; s < WFT_ELL; s += 64) p.ellfT[r * WFT_ELL + s] = 0;
    if (lane == 0) p.degfT[r] = deg;
  }

  const int gid = bid * NTHR + tid, ntot = nblk * NTHR;
  for (int i = gid; i < B * NS; i += ntot)
    p.xp_s[i] = p.x_hist[((size_t)(i / NS) * TH + (TH - 1)) * NS + (i % NS)];
  for (int i = gid; i < B * NC; i += ntot)
    p.xp_c[i] = p.c_x_hist[((size_t)(i / NC) * TH + (TH - 1)) * NC + (i % NC)];

  // weight fragments: u -> (kiter q, tile t, lane l, j); k = q*32 + (l>>4)*8 + j
  for (int u = gid; u < WFRAG; u += ntot) {
    int j = u & 7, l = (u >> 3) & 63, t = (u >> 9) & 15, q = u >> 13;
    int k = q * 32 + ((l >> 4) << 3) + j;
    int c = t * 16 + (l & 15);
    float ws = wcat_val(k, c, p.gru_wi, p.gru_wh, p.gru_bi, p.gru_bh);
    unsigned short hh = bf16rn(ws);
    p.wSh[u] = hh;
    p.wSl[u] = bf16rn(ws - bf16tof(hh));
    float wc = wcat_val(k, c, p.c_gru_wi, p.c_gru_wh, p.c_gru_bi, p.c_gru_bh);
    hh = bf16rn(wc);
    p.wCh[u] = hh;
    p.wCl[u] = bf16rn(wc - bf16tof(hh));
  }
  // xcat init: zeros, col 156 = 1.0 (bias row)
  for (int u = gid; u < NBLK * ROWS * XCW; u += ntot) {
    p.xcat[u] = ((u % XCW) == 156) ? 1.0f : 0.0f;
  }
}

__device__ void ellv_fill(const Params& p, int gid, int ntot) {
  for (int s = gid; s < NS * WS_ELL; s += ntot) {
    int r = s >> 6, k = s & (WS_ELL - 1);
    p.ellv_s[s] = (k < p.deg_s[r]) ? -p.dinv_s[r] * p.dinv_s[p.ellc_s[s]] : 0.0f;
  }
  for (int s = gid; s < NC * WS_ELL; s += ntot) {
    int r = s >> 6, k = s & (WS_ELL - 1);
    p.ellv_c[s] = (k < p.deg_c[r]) ? -p.dinv_c[r] * p.dinv_c[p.ellc_c[s]] : 0.0f;
  }
}

// ---------------- phase A: cheb conv -> sigmoid -> global xg (+ x into xcat) ----------------
__device__ __forceinline__ void phaseA(const Params& p, int bid, int tid, int hist, int step,
                                       Smem* sm) {
  float* xcb = p.xcat + (size_t)bid * (ROWS * XCW);
  for (int q = tid; q < ROWS * DIN; q += NTHR) {
    int i = q / DIN, f = q % DIN;
    int sta = (i < SROWS);
    int b, n;
    const int* cc; const float* vv; int trip;
    if (sta) {
      int smn = bid * SROWS + i; b = smn >> 12; n = smn & 4095;
      cc = &p.ellc_s[n * WS_ELL]; vv = &p.ellv_s[n * WS_ELL];
      trip = (p.deg_s[n] + 7) & ~7;
    } else {
      int cm = bid * CROWS + (i - SROWS); b = cm >> 8; n = cm & 255;
      cc = &p.ellc_c[n * WS_ELL]; vv = &p.ellv_c[n * WS_ELL];
      trip = (p.deg_c[n] + 7) & ~7;
    }
    float xv = xval(p, sta, hist, step, b, n, f);
    sm->u.a.xa[i][f] = xv;
    xcb[i * XCW + f] = xv;
    float acc = 0.0f;
    for (int e = 0; e < trip; e += 8) {   // 8 independent gathers in flight
      int4 c0 = *(const int4*)(cc + e);
      int4 c1 = *(const int4*)(cc + e + 4);
      float4 v0 = *(const float4*)(vv + e);
      float4 v1 = *(const float4*)(vv + e + 4);
      float a0 = xval(p, sta, hist, step, b, c0.x, f);
      float a1 = xval(p, sta, hist, step, b, c0.y, f);
      float a2 = xval(p, sta, hist, step, b, c0.z, f);
      float a3 = xval(p, sta, hist, step, b, c0.w, f);
      float a4 = xval(p, sta, hist, step, b, c1.x, f);
      float a5 = xval(p, sta, hist, step, b, c1.y, f);
      float a6 = xval(p, sta, hist, step, b, c1.z, f);
      float a7 = xval(p, sta, hist, step, b, c1.w, f);
      acc += v0.x * a0 + v0.y * a1 + v0.z * a2 + v0.w * a3
           + v1.x * a4 + v1.y * a5 + v1.z * a6 + v1.w * a7;
    }
    sm->u.a.lx[i][f] = acc;
  }
  __syncthreads();
  for (int q = tid; q < ROWS * G; q += NTHR) {
    int i = q >> 6, g = q & 63;
    int sta = (i < SROWS);
    const float* W = sta ? p.conv_w : p.c_conv_w;
    float acc = (sta ? p.conv_b : p.c_conv_b)[g];
#pragma unroll 4
    for (int f = 0; f < DIN; f++)
      acc += sm->u.a.xa[i][f] * W[f * G + g] + sm->u.a.lx[i][f] * W[DIN * G + f * G + g];
    float s = sigm_(acc);
    if (sta) p.xg_s[(size_t)(bid * SROWS + i) * G + g] = s;
    else     p.xg_c[(size_t)(bid * CROWS + (i - SROWS)) * G + g] = s;
  }
}

// ---------------- phase B: fuse + MFMA GRU GEMM + epilogue ----------------
__device__ __forceinline__ void phaseB(const Params& p, int bid, int tid, int hist, int step,
                                       int idx, Smem* sm) {
  float* xcb = p.xcat + (size_t)bid * (ROWS * XCW);
  // B1 stations (deg~4): one thread per (i,g)
#pragma unroll
  for (int k = 0; k < (SROWS * G) / NTHR; k++) {   // 8
    int q = tid + k * NTHR;
    int i = q >> 6, g = q & 63;
    int smn = bid * SROWS + i; int b = smn >> 12; int r = smn & 4095;
    int dg = p.degf[r];
    const int* cc = &p.ellf[r * WF_ELL];
    size_t bb = (size_t)b * NC;
    float acc = 0.0f;
    int e = 0;
    for (; e + 4 <= dg; e += 4) {
      acc += p.xg_c[(bb + cc[e]) * G + g] + p.xg_c[(bb + cc[e + 1]) * G + g]
           + p.xg_c[(bb + cc[e + 2]) * G + g] + p.xg_c[(bb + cc[e + 3]) * G + g];
    }
    for (; e < dg; e++) acc += p.xg_c[(bb + cc[e]) * G + g];
    sm->u.buf[i][g] = acc;
  }
  // B1 cities (deg~64-96): 8 threads per (ci,g), width-8 shuffle reduce
#pragma unroll
  for (int pass = 0; pass < (CROWS * G * 8) / NTHR; pass++) {   // 4
    int item = tid + pass * NTHR;
    int oct = item & 7;
    int g = (item >> 3) & 63;
    int ci = item >> 9;
    int cm = bid * CROWS + ci; int b = cm >> 8; int r = cm & 255;
    int dg = p.degfT[r];
    const int* cc = &p.ellfT[r * WFT_ELL];
    int dq = (dg + 7) >> 3;
    int e0 = oct * dq;
    int e1 = e0 + dq; if (e1 > dg) e1 = dg; if (e0 > dg) e0 = dg;
    size_t bb = (size_t)b * NS;
    float acc = 0.0f;
    int e = e0;
    for (; e + 4 <= e1; e += 4) {
      acc += p.xg_s[(bb + cc[e]) * G + g] + p.xg_s[(bb + cc[e + 1]) * G + g]
           + p.xg_s[(bb + cc[e + 2]) * G + g] + p.xg_s[(bb + cc[e + 3]) * G + g];
    }
    for (; e < e1; e++) acc += p.xg_s[(bb + cc[e]) * G + g];
    acc += __shfl_down(acc, 4, 8);
    acc += __shfl_down(acc, 2, 8);
    acc += __shfl_down(acc, 1, 8);
    if (oct == 0) sm->u.buf[SROWS + ci][g] = acc;
  }
  __syncthreads();

  // B2: fused = own_xg + gather@Wm + b -> xcat cols 28..91
  for (int q = tid; q < ROWS * G; q += NTHR) {
    int i = q >> 6, g = q & 63;
    int sta = (i < SROWS);
    const float* Wm = sta ? p.c2s_w : p.s2c_w;
    float acc = (sta ? p.c2s_b : p.s2c_b)[g];
#pragma unroll 4
    for (int f = 0; f < G; f++) acc += sm->u.buf[i][f] * Wm[f * G + g];
    float own = sta ? p.xg_s[(size_t)(bid * SROWS + i) * G + g]
                    : p.xg_c[(size_t)(bid * CROWS + (i - SROWS)) * G + g];
    xcb[i * XCW + 28 + g] = own + acc;
  }
  __threadfence();
  __syncthreads();

  // B3: MFMA GEMM gates[80 x 256] = xcat[80 x 160] @ Wcat[160 x 256], bf16 3-term split.
  // 8 waves: wave w -> station row-tile rt=w>>1; wave-pair halves hf=w&1 split N-tiles:
  // tile t = g4*4 + hf*2 + sub (g4: gate group r/z/xn/hc, sub 0..1). Waves 0..3 also do city.
  const int l = tid & 63;
  const int w = tid >> 6;
  const int hf = w & 1;
  const int rt = w >> 1;
  f32x4 accS[8];
  f32x4 accC[4];
#pragma unroll
  for (int t = 0; t < 8; t++) { accS[t][0] = 0.f; accS[t][1] = 0.f; accS[t][2] = 0.f; accS[t][3] = 0.f; }
#pragma unroll
  for (int t = 0; t < 4; t++) { accC[t][0] = 0.f; accC[t][1] = 0.f; accC[t][2] = 0.f; accC[t][3] = 0.f; }
  const bf16x8* WSh = (const bf16x8*)p.wSh;
  const bf16x8* WSl = (const bf16x8*)p.wSl;
  const bf16x8* WCh = (const bf16x8*)p.wCh;
  const bf16x8* WCl = (const bf16x8*)p.wCl;

  for (int q = 0; q < KIT; q++) {
    int kc = q * 32 + ((l >> 4) << 3);
    bf16x8 aSh, aSl, aCh, aCl;
    {
      float av[8];
      const float4* s4 = (const float4*)(xcb + (rt * 16 + (l & 15)) * XCW + kc);
      float4 v0 = s4[0], v1 = s4[1];
      av[0] = v0.x; av[1] = v0.y; av[2] = v0.z; av[3] = v0.w;
      av[4] = v1.x; av[5] = v1.y; av[6] = v1.z; av[7] = v1.w;
      split8(av, aSh, aSl);
    }
    if (w < 4) {
      if ((l & 15) < 4) {
        float av[8];
        const float4* s4 = (const float4*)(xcb + (SROWS + (l & 15)) * XCW + kc);
        float4 v0 = s4[0], v1 = s4[1];
        av[0] = v0.x; av[1] = v0.y; av[2] = v0.z; av[3] = v0.w;
        av[4] = v1.x; av[5] = v1.y; av[6] = v1.z; av[7] = v1.w;
        split8(av, aCh, aCl);
      } else {
#pragma unroll
        for (int j = 0; j < 8; j++) { aCh[j] = 0; aCl[j] = 0; }
      }
    }
    int base = q * (NT * 64) + l;
#pragma unroll
    for (int g4 = 0; g4 < 4; g4++) {
#pragma unroll
      for (int sub = 0; sub < 2; sub++) {
        int t = g4 * 4 + hf * 2 + sub;
        int u = g4 * 2 + sub;
        bf16x8 wh_ = WSh[base + t * 64];
        bf16x8 wl_ = WSl[base + t * 64];
        accS[u] = __builtin_amdgcn_mfma_f32_16x16x32_bf16(aSh, wh_, accS[u], 0, 0, 0);
        accS[u] = __builtin_amdgcn_mfma_f32_16x16x32_bf16(aSl, wh_, accS[u], 0, 0, 0);
        accS[u] = __builtin_amdgcn_mfma_f32_16x16x32_bf16(aSh, wl_, accS[u], 0, 0, 0);
      }
    }
    if (w < 4) {
#pragma unroll
      for (int tt = 0; tt < 4; tt++) {
        int t = w + tt * 4;
        bf16x8 wh_ = WCh[base + t * 64];
        bf16x8 wl_ = WCl[base + t * 64];
        accC[tt] = __builtin_amdgcn_mfma_f32_16x16x32_bf16(aCh, wh_, accC[tt], 0, 0, 0);
        accC[tt] = __builtin_amdgcn_mfma_f32_16x16x32_bf16(aCl, wh_, accC[tt], 0, 0, 0);
        accC[tt] = __builtin_amdgcn_mfma_f32_16x16x32_bf16(aCh, wl_, accC[tt], 0, 0, 0);
      }
    }
  }
  __syncthreads();   // all A-frag reads done before h region is overwritten

  const int pred = !hist;
  const int t_out = step - (TH - 1);
  // station epilogue: C layout col=lane&15, row=(lane>>4)*4+reg. Wave w: rows rt*16..+15,
  // gate cols j = (hf*2+sub)*16 + (l&15), sub 0..1.
  {
    float fcacc[4] = {0.f, 0.f, 0.f, 0.f};
#pragma unroll
    for (int sub = 0; sub < 2; sub++) {
      int grp = hf * 2 + sub;
      int j = grp * 16 + (l & 15);
      int upd = ((idx & ((1 << grp) - 1)) == 0);
      float fwj = p.fc_w[j];
#pragma unroll
      for (int r = 0; r < 4; r++) {
        int row = rt * 16 + ((l >> 4) << 2) + r;
        float rr = sigm_(accS[0 * 2 + sub][r]);
        float zz = sigm_(accS[1 * 2 + sub][r]);
        float nn = tanhf(accS[2 * 2 + sub][r] + rr * accS[3 * 2 + sub][r]);
        float* hp = xcb + row * XCW + 92 + j;
        float ho = *hp;
        float hn = upd ? ((1.0f - zz) * nn + zz * ho) : ho;
        *hp = hn;
        fcacc[r] += fwj * hn;
      }
    }
    if (pred) {
#pragma unroll
      for (int r = 0; r < 4; r++) {
        float v = fcacc[r];
        v += __shfl_down(v, 8, 16);
        v += __shfl_down(v, 4, 16);
        v += __shfl_down(v, 2, 16);
        v += __shfl_down(v, 1, 16);
        if ((l & 15) == 0) {
          int row = rt * 16 + ((l >> 4) << 2) + r;
          sm->fcS[row][hf] = v;
        }
      }
    }
  }
  // city epilogue: waves 0..3, lanes 0..15 hold rows 0..3 in regs
  if (w < 4) {
    float cfc[4] = {0.f, 0.f, 0.f, 0.f};
    if ((l >> 4) == 0) {
      int j = w * 16 + (l & 15);
      int upd = ((idx & ((1 << w) - 1)) == 0);
      float fwj = p.c_fc_w[j];
#pragma unroll
      for (int r = 0; r < 4; r++) {
        float rr = sigm_(accC[0][r]);
        float zz = sigm_(accC[1][r]);
        float nn = tanhf(accC[2][r] + rr * accC[3][r]);
        float* hp = xcb + (SROWS + r) * XCW + 92 + j;
        float ho = *hp;
        float hn = upd ? ((1.0f - zz) * nn + zz * ho) : ho;
        *hp = hn;
        cfc[r] = fwj * hn;
      }
    }
    if (pred) {
#pragma unroll
      for (int r = 0; r < 4; r++) {
        float v = cfc[r];
        v += __shfl_down(v, 8, 16);
        v += __shfl_down(v, 4, 16);
        v += __shfl_down(v, 2, 16);
        v += __shfl_down(v, 1, 16);
        if (l == 0) sm->cityfc[w][r] = v;
      }
    }
  }
  if (pred) {
    __syncthreads();
    if (tid < SROWS) {
      int row = tid;
      float y = sm->fcS[row][0] + sm->fcS[row][1] + p.fc_b[0];
      int smn = bid * SROWS + row; int b = smn >> 12; int n = smn & 4095;
      p.out[((size_t)b * TP + t_out) * NS + n] = y;
      p.xp_s[smn] = y;
    } else if (tid < SROWS + CROWS) {
      int ci = tid - SROWS;
      float y = sm->cityfc[0][ci] + sm->cityfc[1][ci] + sm->cityfc[2][ci] +
                sm->cityfc[3][ci] + p.c_fc_b[0];
      int cm = bid * CROWS + ci; int b = cm >> 8; int n = cm & 255;
      p.out[(size_t)B * TP * NS + ((size_t)b * TP + t_out) * NC + n] = y;
      p.xp_c[cm] = y;
    }
  }
}

// ---------------- kernels ----------------
__global__ __launch_bounds__(NTHR, 4) void persist_kernel(Params p) {
  cg::grid_group grid = cg::this_grid();
  __shared__ Smem sm;
  build_tables(p, blockIdx.x, threadIdx.x, gridDim.x);
  grid.sync();
  ellv_fill(p, blockIdx.x * NTHR + threadIdx.x, gridDim.x * NTHR);
  grid.sync();
  for (int step = 0; step < NSTEP; step++) {
    int hist = (step < TH - 1) ? 1 : 0;
    phaseA(p, blockIdx.x, threadIdx.x, hist, step, &sm);
    grid.sync();
    phaseB(p, blockIdx.x, threadIdx.x, hist, step, step + 1, &sm);
    grid.sync();
  }
}

__global__ __launch_bounds__(NTHR, 4) void build_kernel(Params p) {
  build_tables(p, blockIdx.x, threadIdx.x, gridDim.x);
}
__global__ __launch_bounds__(NTHR, 4) void ellv_kernel(Params p) {
  ellv_fill(p, blockIdx.x * NTHR + threadIdx.x, gridDim.x * NTHR);
}
__global__ __launch_bounds__(NTHR, 4) void stepA_kernel(Params p, int step, int hist) {
  __shared__ Smem sm;
  phaseA(p, blockIdx.x, threadIdx.x, hist, step, &sm);
}
__global__ __launch_bounds__(NTHR, 4) void stepB_kernel(Params p, int step, int hist, int idx) {
  __shared__ Smem sm;
  phaseB(p, blockIdx.x, threadIdx.x, hist, step, idx, &sm);
}

extern "C" void kernel_launch(void* const* d_in, const int* in_sizes, int n_in,
                              void* d_out, int out_size, void* d_ws, size_t ws_size,
                              hipStream_t stream) {
  Params p;
  p.x_hist   = (const float*)d_in[0];
  p.feat_s   = (const float*)d_in[1];
  p.c_x_hist = (const float*)d_in[2];
  p.feat_c   = (const float*)d_in[3];
  p.adj_s    = (const float*)d_in[4];
  p.adj_c    = (const float*)d_in[5];
  p.afc      = (const float*)d_in[6];
  p.conv_w   = (const float*)d_in[7];
  p.conv_b   = (const float*)d_in[8];
  p.c_conv_w = (const float*)d_in[9];
  p.c_conv_b = (const float*)d_in[10];
  p.gru_wi   = (const float*)d_in[11];
  p.gru_wh   = (const float*)d_in[12];
  p.gru_bi   = (const float*)d_in[13];
  p.gru_bh   = (const float*)d_in[14];
  p.c_gru_wi = (const float*)d_in[15];
  p.c_gru_wh = (const float*)d_in[16];
  p.c_gru_bi = (const float*)d_in[17];
  p.c_gru_bh = (const float*)d_in[18];
  p.fc_w     = (const float*)d_in[19];
  p.fc_b     = (const float*)d_in[20];
  p.c_fc_w   = (const float*)d_in[21];
  p.c_fc_b   = (const float*)d_in[22];
  p.c2s_w    = (const float*)d_in[23];
  p.c2s_b    = (const float*)d_in[24];
  p.s2c_w    = (const float*)d_in[25];
  p.s2c_b    = (const float*)d_in[26];

  char* wp = (char*)d_ws;
  auto alloc = [&](size_t bytes) -> char* {
    char* q = wp;
    wp += (bytes + 255) & ~(size_t)255;
    return q;
  };
  p.deg_s  = (int*)alloc(NS * 4);
  p.dinv_s = (float*)alloc(NS * 4);
  p.ellc_s = (int*)alloc((size_t)NS * WS_ELL * 4);
  p.ellv_s = (float*)alloc((size_t)NS * WS_ELL * 4);
  p.deg_c  = (int*)alloc(NC * 4);
  p.dinv_c = (float*)alloc(NC * 4);
  p.ellc_c = (int*)alloc((size_t)NC * WS_ELL * 4);
  p.ellv_c = (float*)alloc((size_t)NC * WS_ELL * 4);
  p.degf   = (int*)alloc(NS * 4);
  p.ellf   = (int*)alloc((size_t)NS * WF_ELL * 4);
  p.degfT  = (int*)alloc(NC * 4);
  p.ellfT  = (int*)alloc((size_t)NC * WFT_ELL * 4);
  p.xg_s   = (float*)alloc((size_t)B * NS * G * 4);
  p.xg_c   = (float*)alloc((size_t)B * NC * G * 4);
  p.xp_s   = (float*)alloc((size_t)B * NS * 4);
  p.xp_c   = (float*)alloc((size_t)B * NC * 4);
  p.xcat   = (float*)alloc((size_t)NBLK * ROWS * XCW * 4);
  p.wSh    = (unsigned short*)alloc((size_t)WFRAG * 2);
  p.wSl    = (unsigned short*)alloc((size_t)WFRAG * 2);
  p.wCh    = (unsigned short*)alloc((size_t)WFRAG * 2);
  p.wCl    = (unsigned short*)alloc((size_t)WFRAG * 2);
  p.out    = (float*)d_out;

  int dev = 0;
  hipGetDevice(&dev);
  int coopAttr = 0, numCU = 0, maxActive = 0;
  hipDeviceGetAttribute(&coopAttr, hipDeviceAttributeCooperativeLaunch, dev);
  hipDeviceGetAttribute(&numCU, hipDeviceAttributeMultiprocessorCount, dev);
  hipError_t oe = hipOccupancyMaxActiveBlocksPerMultiprocessor(
      &maxActive, (const void*)persist_kernel, NTHR, 0);

  hipError_t le = hipErrorUnknown;
  if (coopAttr && oe == hipSuccess && (long)maxActive * numCU >= NBLK) {
    void* kargs[] = { (void*)&p };
    le = hipLaunchCooperativeKernel((const void*)persist_kernel, dim3(NBLK), dim3(NTHR),
                                    kargs, 0, stream);
  }
  if (le != hipSuccess) {
    build_kernel<<<NBLK, NTHR, 0, stream>>>(p);
    ellv_kernel<<<NBLK, NTHR, 0, stream>>>(p);
    for (int step = 0; step < NSTEP; step++) {
      int hist = (step < TH - 1) ? 1 : 0;
      stepA_kernel<<<NBLK, NTHR, 0, stream>>>(p, step, hist);
      stepB_kernel<<<NBLK, NTHR, 0, stream>>>(p, step, hist, step + 1);
    }
  }
}